// Round 4
// baseline (334.573 us; speedup 1.0000x reference)
//
#include <hip/hip_runtime.h>
#include <hip/hip_bf16.h>
#include <math.h>
#include <float.h>

#define B       32
#define S_CURR  128
#define D       512
#define H       8
#define DH      64
#define NM      16
#define NCAND   39998          // emb[2:]
#define MG      (B * NM)       // 512 gathered rows
#define SCLD    40064          // padded row count of embB / col stride of scB
#define NT2     157            // ceil(NCAND/256) N-tiles (256-wide)

typedef __bf16 bf16x8_t __attribute__((ext_vector_type(8)));
typedef float  f32x4_t  __attribute__((ext_vector_type(4)));

typedef __attribute__((address_space(3))) unsigned int lds_u32_t;
typedef const __attribute__((address_space(1))) unsigned int gbl_u32_t;

__device__ __forceinline__ void async16(const void* g, void* l) {
    __builtin_amdgcn_global_load_lds((gbl_u32_t*)g, (lds_u32_t*)l, 16, 0, 0);
}

// ---------------------------------------------------------------------------
// Prep kernel: bx < 10512 -> f32->bf16 converts (emb[2:], 4 weight mats);
// 10512 <= bx < 14608 -> currB = bf16(emb[idx]+pe); bx == 14608 -> qidx.
// ---------------------------------------------------------------------------
__global__ __launch_bounds__(256) void prep_kernel(
    const float* __restrict__ emb,
    const float* __restrict__ wq, const float* __restrict__ wk,
    const float* __restrict__ wv, const float* __restrict__ t2w,
    __bf16* __restrict__ embB, __bf16* __restrict__ wqB, __bf16* __restrict__ wkB,
    __bf16* __restrict__ wvB, __bf16* __restrict__ t2wB,
    const int* __restrict__ curr_idx, __bf16* __restrict__ currB,
    const int* __restrict__ mask_pos, int* __restrict__ qidx)
{
    int bx = blockIdx.x;
    if (bx < 10512) {
        const float* src; __bf16* dst; size_t n, base;
        if (bx < 10000) {
            src = emb + 2 * D; dst = embB; n = (size_t)NCAND * D; base = (size_t)bx * 2048;
        } else {
            int w = (bx - 10000) >> 7;
            base = (size_t)((bx - 10000) & 127) * 2048;
            n = (size_t)D * D;
            src = (w == 0) ? wq : (w == 1) ? wk : (w == 2) ? wv : t2w;
            dst = (w == 0) ? wqB : (w == 1) ? wkB : (w == 2) ? wvB : t2wB;
        }
        size_t i = base + (size_t)threadIdx.x * 8;
        if (i >= n) return;
        float4 a = *(const float4*)(src + i);
        float4 b = *(const float4*)(src + i + 4);
        bf16x8_t v;
        v[0] = (__bf16)a.x; v[1] = (__bf16)a.y; v[2] = (__bf16)a.z; v[3] = (__bf16)a.w;
        v[4] = (__bf16)b.x; v[5] = (__bf16)b.y; v[6] = (__bf16)b.z; v[7] = (__bf16)b.w;
        *(bf16x8_t*)(dst + i) = v;
        return;
    }
    if (bx == 14608) {
        int r = threadIdx.x;
        qidx[r] = (r >> 4) * S_CURR + mask_pos[r];
        r += 256;
        qidx[r] = (r >> 4) * S_CURR + mask_pos[r];
        return;
    }
    int bs = bx - 10512;
    int s = bs & (S_CURR - 1);
    int g = curr_idx[bs];
    const float* e = emb + (size_t)g * D;
    __bf16* o = currB + (size_t)bs * D;
    int d = threadIdx.x * 2;
    float div = expf(-(float)d * (9.210340371976184f / 512.0f));
    float ang = (float)s * div;
    o[d]     = (__bf16)(e[d]     + sinf(ang));
    o[d + 1] = (__bf16)(e[d + 1] + cosf(ang));
}

// ---------------------------------------------------------------------------
// bf16 GEMM (QKV + t2): C = A @ W^T + bias, K=512, N=512, 128x128 tile,
// double-buffered global_load_lds prefetch (prefetch issued before compute so
// the barrier's vmcnt(0) drain overlaps MFMA). Swizzled LDS (0 bank conflicts).
// ---------------------------------------------------------------------------
__global__ __launch_bounds__(256) void gemm_bf(
    const __bf16* __restrict__ A,
    const __bf16* __restrict__ W0, const float* __restrict__ b0, __bf16* __restrict__ C0,
    const __bf16* __restrict__ W1, const float* __restrict__ b1, __bf16* __restrict__ C1,
    const __bf16* __restrict__ W2, const float* __restrict__ b2, __bf16* __restrict__ C2,
    const int* __restrict__ rowidx)
{
    const int z = blockIdx.z;
    if (z == 2 && blockIdx.x >= 4) return;   // Q problem has M=512 only
    const __bf16* W = (z == 0) ? W0 : (z == 1) ? W1 : W2;
    const float* bias = (z == 0) ? b0 : (z == 1) ? b1 : b2;
    __bf16* C = (z == 0) ? C0 : (z == 1) ? C1 : C2;

    __shared__ __bf16 As[2][128 * 64];
    __shared__ __bf16 Bs[2][128 * 64];

    const int tid = threadIdx.x, lane = tid & 63, wave = tid >> 6;
    const int wy = wave >> 1, wx = wave & 1;
    const int m0 = blockIdx.x * 128, n0 = blockIdx.y * 128;
    const int lrow = lane >> 3;
    const int lcol = (((lane & 7) ^ lrow) & 7) * 8;   // swizzled source granule

    const __bf16* aptr[4]; const __bf16* bptr[4];
#pragma unroll
    for (int i = 0; i < 4; ++i) {
        int chunk = wave * 4 + i;
        int ar = m0 + chunk * 8 + lrow;
        if (z == 2) ar = rowidx[ar];
        aptr[i] = A + (size_t)ar * 512 + lcol;
        bptr[i] = W + (size_t)(n0 + chunk * 8 + lrow) * 512 + lcol;
    }

    f32x4_t acc[4][4];
#pragma unroll
    for (int i = 0; i < 4; ++i)
#pragma unroll
        for (int j = 0; j < 4; ++j) acc[i][j] = (f32x4_t){0.f, 0.f, 0.f, 0.f};

    const int l7 = lane & 7, quad = lane >> 4, c16 = lane & 15;

    // prologue: stage iter 0 into buffer 0
#pragma unroll
    for (int i = 0; i < 4; ++i) {
        int chunk = wave * 4 + i;
        async16(aptr[i], &As[0][chunk * 512]);
        async16(bptr[i], &Bs[0][chunk * 512]);
    }
    __syncthreads();

    for (int it = 0; it < 8; ++it) {
        const int cur = it & 1;
        if (it < 7) {
            const int kk = (it + 1) * 64;
#pragma unroll
            for (int i = 0; i < 4; ++i) {
                int chunk = wave * 4 + i;
                async16(aptr[i] + kk, &As[cur ^ 1][chunk * 512]);
                async16(bptr[i] + kk, &Bs[cur ^ 1][chunk * 512]);
            }
        }
#pragma unroll
        for (int kb = 0; kb < 2; ++kb) {
            const int goff = ((kb * 4 + quad) ^ l7) * 8;
            bf16x8_t af[4], bfv[4];
#pragma unroll
            for (int i = 0; i < 4; ++i)
                af[i] = *(const bf16x8_t*)&As[cur][(wy * 64 + i * 16 + c16) * 64 + goff];
#pragma unroll
            for (int j = 0; j < 4; ++j)
                bfv[j] = *(const bf16x8_t*)&Bs[cur][(wx * 64 + j * 16 + c16) * 64 + goff];
#pragma unroll
            for (int i = 0; i < 4; ++i)
#pragma unroll
                for (int j = 0; j < 4; ++j)
                    acc[i][j] = __builtin_amdgcn_mfma_f32_16x16x32_bf16(
                        af[i], bfv[j], acc[i][j], 0, 0, 0);
        }
        __syncthreads();
    }

#pragma unroll
    for (int i = 0; i < 4; ++i)
#pragma unroll
        for (int j = 0; j < 4; ++j) {
            int col = n0 + wx * 64 + j * 16 + c16;
            float bv = bias[col];
#pragma unroll
            for (int rr = 0; rr < 4; ++rr) {
                int row = m0 + wy * 64 + i * 16 + quad * 4 + rr;
                C[(size_t)row * 512 + col] = (__bf16)(acc[i][j][rr] + bv);
            }
        }
}

// ---------------------------------------------------------------------------
// Scores GEMM + softmax partials. 128x256 tile, 4 waves of 64x128 (acc 4x8),
// double-buffered prefetch. 1-D grid 640: xcd = bid&7 owns N2-tiles
// [xcd*20, xcd*20+20); its 4 M-blocks are bid-consecutive (stride 8) so they
// co-run on the same XCD and share the B-strip in that XCD's L2.
// For the last N2-tile, B rows beyond embB are masked garbage (cols >= NCAND).
// ---------------------------------------------------------------------------
__global__ __launch_bounds__(256, 1) void gemm_scores(
    const __bf16* __restrict__ A,      // 512 x 512 (gatheredB)
    const __bf16* __restrict__ Bm,     // 40064(pad) x 512 (embB)
    __bf16* __restrict__ scB,          // 512 x SCLD
    float* __restrict__ pmax, float* __restrict__ psum)
{
    const int bid = blockIdx.x;
    const int xcd = bid & 7, k = bid >> 3;       // k: 0..79
    const int n2 = xcd * 20 + (k >> 2);
    if (n2 >= NT2) return;
    const int m0 = (k & 3) * 128, n0 = n2 * 256;

    __shared__ __bf16 As[2][128 * 64];           // 2 x 16 KB
    __shared__ __bf16 Bs[2][256 * 64];           // 2 x 32 KB
    __shared__ float redm[2][128], reds[2][128];

    const int tid = threadIdx.x, lane = tid & 63, wave = tid >> 6;
    const int wy = wave & 1, wx = wave >> 1;     // row half / col half
    const int lrow = lane >> 3;
    const int lcol = (((lane & 7) ^ lrow) & 7) * 8;

    const __bf16* aptr[4]; const __bf16* bptr[8];
#pragma unroll
    for (int i = 0; i < 4; ++i)
        aptr[i] = A + (size_t)(m0 + (wave * 4 + i) * 8 + lrow) * 512 + lcol;
#pragma unroll
    for (int i = 0; i < 8; ++i)
        bptr[i] = Bm + (size_t)(n0 + (wave * 8 + i) * 8 + lrow) * 512 + lcol;

    f32x4_t acc[4][8];
#pragma unroll
    for (int i = 0; i < 4; ++i)
#pragma unroll
        for (int j = 0; j < 8; ++j) acc[i][j] = (f32x4_t){0.f, 0.f, 0.f, 0.f};

    const int l7 = lane & 7, quad = lane >> 4, c16 = lane & 15;

    // prologue
#pragma unroll
    for (int i = 0; i < 4; ++i) async16(aptr[i], &As[0][(wave * 4 + i) * 512]);
#pragma unroll
    for (int i = 0; i < 8; ++i) async16(bptr[i], &Bs[0][(wave * 8 + i) * 512]);
    __syncthreads();

    for (int it = 0; it < 8; ++it) {
        const int cur = it & 1;
        if (it < 7) {
            const int kk = (it + 1) * 64;
#pragma unroll
            for (int i = 0; i < 4; ++i)
                async16(aptr[i] + kk, &As[cur ^ 1][(wave * 4 + i) * 512]);
#pragma unroll
            for (int i = 0; i < 8; ++i)
                async16(bptr[i] + kk, &Bs[cur ^ 1][(wave * 8 + i) * 512]);
        }
#pragma unroll
        for (int kb = 0; kb < 2; ++kb) {
            const int goff = ((kb * 4 + quad) ^ l7) * 8;
            bf16x8_t af[4], bfv[8];
#pragma unroll
            for (int i = 0; i < 4; ++i)
                af[i] = *(const bf16x8_t*)&As[cur][(wy * 64 + i * 16 + c16) * 64 + goff];
#pragma unroll
            for (int j = 0; j < 8; ++j)
                bfv[j] = *(const bf16x8_t*)&Bs[cur][(wx * 128 + j * 16 + c16) * 64 + goff];
#pragma unroll
            for (int i = 0; i < 4; ++i)
#pragma unroll
                for (int j = 0; j < 8; ++j)
                    acc[i][j] = __builtin_amdgcn_mfma_f32_16x16x32_bf16(
                        af[i], bfv[j], acc[i][j], 0, 0, 0);
        }
        __syncthreads();
    }

    // Epilogue: bf16 store + max-then-exp softmax partials.
#pragma unroll
    for (int i = 0; i < 4; ++i) {
#pragma unroll
        for (int rr = 0; rr < 4; ++rr) {
            const int row = wy * 64 + i * 16 + quad * 4 + rr;   // local 0..127
            const size_t rowbase = (size_t)(m0 + row) * SCLD;
            float v[8]; float m = -FLT_MAX;
#pragma unroll
            for (int j = 0; j < 8; ++j) {
                int col = n0 + wx * 128 + j * 16 + c16;
                __bf16 xb = (__bf16)acc[i][j][rr];
                if (col < NCAND) {
                    scB[rowbase + col] = xb;
                    v[j] = (float)xb; m = fmaxf(m, v[j]);
                } else v[j] = -FLT_MAX;
            }
#pragma unroll
            for (int mk = 1; mk < 16; mk <<= 1)
                m = fmaxf(m, __shfl_xor(m, mk));
            float s = 0.f;
#pragma unroll
            for (int j = 0; j < 8; ++j)
                if (v[j] > -FLT_MAX) s += __expf(v[j] - m);
#pragma unroll
            for (int mk = 1; mk < 16; mk <<= 1)
                s += __shfl_xor(s, mk);
            if (c16 == 0) { redm[wx][row] = m; reds[wx][row] = s; }
        }
    }
    __syncthreads();
    if (tid < 128) {
        float ma = redm[0][tid], sa = reds[0][tid];
        float mb = redm[1][tid], sb = reds[1][tid];
        float mm = fmaxf(ma, mb);
        float ss = sa * __expf(ma - mm) + sb * __expf(mb - mm);
        pmax[(size_t)n2 * MG + m0 + tid] = mm;
        psum[(size_t)n2 * MG + m0 + tid] = ss;
    }
}

// ---------------------------------------------------------------------------
// Attention: one block per (b,h); K/V/Q head-slices staged in LDS once.
// 256 threads = 16 queries x 16 lanes. tanh fused at write.
// ---------------------------------------------------------------------------
#define KPAD 72
__global__ __launch_bounds__(256) void attn_kernel(const __bf16* __restrict__ Qg,
                                                   const __bf16* __restrict__ K,
                                                   const __bf16* __restrict__ V,
                                                   __bf16* __restrict__ attnB) {
    const int b = blockIdx.x, h = blockIdx.y, t = threadIdx.x;
    __shared__ __bf16 Ks[128 * KPAD];
    __shared__ __bf16 Vs[128 * KPAD];
    __shared__ float  Qs[16 * 68];
    __shared__ float  P[16 * 130];

    for (int i = t; i < 1024; i += 256) {
        int row = i >> 3, cg = (i & 7) * 8;
        size_t gsrc = ((size_t)(b * S_CURR + row)) * D + h * DH + cg;
        *(bf16x8_t*)&Ks[row * KPAD + cg] = *(const bf16x8_t*)&K[gsrc];
        *(bf16x8_t*)&Vs[row * KPAD + cg] = *(const bf16x8_t*)&V[gsrc];
    }
    if (t < 128) {
        int q = t >> 3, cg = (t & 7) * 8;
        bf16x8_t qv = *(const bf16x8_t*)&Qg[((size_t)(b * NM + q)) * D + h * DH + cg];
#pragma unroll
        for (int u = 0; u < 8; ++u) Qs[q * 68 + cg + u] = (float)qv[u];
    }
    __syncthreads();

    const int q = t >> 4, i = t & 15;
    float sv[8];
    float lmax = -FLT_MAX;
#pragma unroll
    for (int z = 0; z < 8; ++z) {
        int kk = i + z * 16;
        float s = 0.f;
#pragma unroll
        for (int d0 = 0; d0 < DH; d0 += 8) {
            bf16x8_t kv = *(const bf16x8_t*)&Ks[kk * KPAD + d0];
#pragma unroll
            for (int u = 0; u < 8; ++u) s += Qs[q * 68 + d0 + u] * (float)kv[u];
        }
        sv[z] = s; lmax = fmaxf(lmax, s);
    }
#pragma unroll
    for (int mk = 1; mk < 16; mk <<= 1) lmax = fmaxf(lmax, __shfl_xor(lmax, mk));
    float lsum = 0.f;
#pragma unroll
    for (int z = 0; z < 8; ++z) {
        float e = __expf(sv[z] - lmax);
        P[q * 130 + i + z * 16] = e;
        lsum += e;
    }
#pragma unroll
    for (int mk = 1; mk < 16; mk <<= 1) lsum += __shfl_xor(lsum, mk);
    const float inv = 1.0f / lsum;

    // P[q][*] produced and consumed by the same wave — no barrier needed.
    const int d = i * 4;
    float a0 = 0.f, a1 = 0.f, a2 = 0.f, a3 = 0.f;
    for (int kk = 0; kk < 128; ++kk) {
        float p = P[q * 130 + kk];
        const __bf16* vr = &Vs[kk * KPAD + d];
        a0 += p * (float)vr[0]; a1 += p * (float)vr[1];
        a2 += p * (float)vr[2]; a3 += p * (float)vr[3];
    }
    __bf16* o = attnB + ((size_t)(b * NM + q)) * D + h * DH + d;
    o[0] = (__bf16)tanhf(a0 * inv); o[1] = (__bf16)tanhf(a1 * inv);
    o[2] = (__bf16)tanhf(a2 * inv); o[3] = (__bf16)tanhf(a3 * inv);
}

// ---------------------------------------------------------------------------
__global__ __launch_bounds__(256) void lse_reduce(const float* __restrict__ pmax,
                                                  const float* __restrict__ psum,
                                                  float* __restrict__ lse) {
    int row = blockIdx.x, t = threadIdx.x;
    float m = -FLT_MAX, s = 0.f;
    for (int i = t; i < NT2; i += 256) {
        float om = pmax[(size_t)i * MG + row];
        float os = psum[(size_t)i * MG + row];
        float mm = fmaxf(m, om);
        s = s * __expf(m - mm) + os * __expf(om - mm);
        m = mm;
    }
    __shared__ float ms[256], ss[256];
    ms[t] = m; ss[t] = s;
    __syncthreads();
    for (int off = 128; off > 0; off >>= 1) {
        if (t < off) {
            float m1 = ms[t], s1 = ss[t], m2 = ms[t + off], s2 = ss[t + off];
            float mm = fmaxf(m1, m2);
            ms[t] = mm;
            ss[t] = (s1 * __expf(m1 - mm)) + (s2 * __expf(m2 - mm));
        }
        __syncthreads();
    }
    if (t == 0) lse[row] = ms[0] + logf(ss[0]);
}

// ---------------------------------------------------------------------------
__global__ __launch_bounds__(256) void final_out(const __bf16* __restrict__ scB,
                                                 const float* __restrict__ lse,
                                                 float* __restrict__ out) {
    int row = blockIdx.y;
    int c0 = (blockIdx.x * 256 + threadIdx.x) * 8;
    if (c0 >= NCAND) return;
    float l = lse[row];
    bf16x8_t v = *(const bf16x8_t*)(scB + (size_t)row * SCLD + c0);
    float* o = out + (size_t)row * NCAND + c0;
    if (c0 + 8 <= NCAND) {
        *(float2*)(o)     = make_float2((float)v[0] - l, (float)v[1] - l);
        *(float2*)(o + 2) = make_float2((float)v[2] - l, (float)v[3] - l);
        *(float2*)(o + 4) = make_float2((float)v[4] - l, (float)v[5] - l);
        *(float2*)(o + 6) = make_float2((float)v[6] - l, (float)v[7] - l);
    } else {
        for (int k2 = 0; k2 < NCAND - c0; ++k2) o[k2] = (float)v[k2] - l;
    }
}

// ---------------------------------------------------------------------------
extern "C" void kernel_launch(void* const* d_in, const int* in_sizes, int n_in,
                              void* d_out, int out_size, void* d_ws, size_t ws_size,
                              hipStream_t stream) {
    const int*   mask_pos = (const int*)d_in[2];
    const int*   curr_idx = (const int*)d_in[3];
    const float* emb      = (const float*)d_in[5];
    const float* c_wq = (const float*)d_in[12];
    const float* c_bq = (const float*)d_in[13];
    const float* c_wk = (const float*)d_in[14];
    const float* c_bk = (const float*)d_in[15];
    const float* c_wv = (const float*)d_in[16];
    const float* c_bv = (const float*)d_in[17];
    const float* t2_w = (const float*)d_in[24];
    const float* t2_b = (const float*)d_in[25];
    float* out = (float*)d_out;

    char* w = (char*)d_ws;
    __bf16* embB  = (__bf16*)w;                           // 40064x512 bf16 = 41 MB
    __bf16* scB   = (__bf16*)(w + 41025536);              // 512x40064 bf16 = 41 MB
    __bf16* currB = scB;                                  // overlay (dead pre-scores)
    __bf16* Kf    = (__bf16*)(w + 41025536 + 4194304);
    __bf16* Vf    = (__bf16*)(w + 41025536 + 8388608);
    __bf16* Qg    = (__bf16*)(w + 41025536 + 12582912);
    __bf16* attnB = (__bf16*)(w + 41025536 + 13107200);
    __bf16* wqB   = (__bf16*)(w + 41025536 + 13631488);
    __bf16* wkB   = (__bf16*)(w + 41025536 + 14155776);
    __bf16* wvB   = (__bf16*)(w + 41025536 + 14680064);
    __bf16* t2wB  = (__bf16*)(w + 41025536 + 15204352);
    int*    qidx  = (int*)   (w + 41025536 + 15728640);
    __bf16* gatheredB = (__bf16*)(w + 82051072);
    float*  pmax  = (float*)(w + 82575360);               // 157*512 f32
    float*  psum  = (float*)(w + 83216384);               // 157*512 f32
    float*  lse   = (float*)(w + 83857408);               // 512 f32

    hipLaunchKernelGGL(prep_kernel, dim3(14609), dim3(256), 0, stream,
                       emb, c_wq, c_wk, c_wv, t2_w, embB, wqB, wkB, wvB, t2wB,
                       curr_idx, currB, mask_pos, qidx);
    // K (z=0), V (z=1), Q-gathered (z=2, only 4 M-tiles) in one dispatch
    hipLaunchKernelGGL(gemm_bf, dim3(32, 4, 3), dim3(256), 0, stream,
                       currB, wkB, c_bk, Kf, wvB, c_bv, Vf, wqB, c_bq, Qg, qidx);
    hipLaunchKernelGGL(attn_kernel, dim3(B, H), dim3(256), 0, stream,
                       Qg, Kf, Vf, attnB);
    hipLaunchKernelGGL(gemm_bf, dim3(4, 4, 1), dim3(256), 0, stream,
                       attnB, t2wB, t2_b, gatheredB,
                       t2wB, t2_b, gatheredB, t2wB, t2_b, gatheredB,
                       (const int*)nullptr);
    hipLaunchKernelGGL(gemm_scores, dim3(640), dim3(256), 0, stream,
                       gatheredB, embB, scB, pmax, psum);
    hipLaunchKernelGGL(lse_reduce, dim3(MG), dim3(256), 0, stream, pmax, psum, lse);
    hipLaunchKernelGGL(final_out, dim3(20, MG), dim3(256), 0, stream, scB, lse, out);
}